// Round 3
// baseline (468.159 us; speedup 1.0000x reference)
//
#include <hip/hip_runtime.h>

// Shapes fixed by the reference: D=128 features, E=128 edges, B=4096 batch.
constexpr int D    = 128;
constexpr int E    = 128;
constexpr int BB   = 4096;
constexpr int ROWS = 8;      // batch rows per prep2 block (fallback path)

typedef float f32x4 __attribute__((ext_vector_type(4)));

// Algebra: m_i = T@W^T + b ; v = m_i@W = T@(W^T W) + b@W = T@G + h
//          c   = m_i . b   = T.h + beta          (h = b@W, beta = b.b)
// e_ij[e,b] = S[e,b,:].v[b,:] + c[b]
//
// Primary path (ws_size >= 64.5 KB): P = d_ws holds [G (D*D) | h (D) | beta].
//   gwh -> att_fused2. att_fused2 handles TWO batch rows per block, computes
//   v,c in-block with a float4-vectorized GEMV (G rows coalesced, each g4
//   load shared by both rows) hidden under the 32-deep nt S-load stream.
// Fallback path (tiny/absent ws): P lives at out[2*BB*D ...] (e=2 slice head),
//   race-free by stream ordering: prep2 consumes P before att_main overwrites.

// ---------------------------------------------------------------------------
// gwh: P = [G = W^T W | h = b@W | beta = b.b]. 128 blocks x 128 threads, ~3us.
// ---------------------------------------------------------------------------
__global__ __launch_bounds__(128) void gwh_kernel(
    const float* __restrict__ W, const float* __restrict__ bias, float* P)
{
    __shared__ float Wl[D][D];   // 64 KB
    __shared__ float bl[D];
    const int t = threadIdx.x;
    const int r = blockIdx.x;

    const float4* W4 = (const float4*)W;
    float4* Wl4 = (float4*)&Wl[0][0];
    for (int i = t; i < D * D / 4; i += 128) Wl4[i] = W4[i];
    bl[t] = bias[t];
    __syncthreads();

    // G[r][t] = sum_k W[k][r] * W[k][t]   (broadcast + stride-1: conflict-free)
    float acc = 0.f;
    for (int k = 0; k < D; ++k) acc += Wl[k][r] * Wl[k][t];
    P[r * D + t] = acc;

    if (r == 0) {
        float hh = 0.f;
        for (int f = 0; f < D; ++f) hh += bl[f] * Wl[f][t];
        P[D * D + t] = hh;
        if (t == 0) {
            float b2 = 0.f;
            for (int f = 0; f < D; ++f) b2 += bl[f] * bl[f];
            P[D * D + D] = b2;
        }
    }
}

// ---------------------------------------------------------------------------
// att_fused2 (primary): 2048 blocks x 256 threads; block handles b0 = 2*bid
// and b1 = b0+1. Both E x D slices register-resident (2 x 64 VGPR). GEMV for
// v: thread (dg = t&31, ks = t>>5) covers d-chunk 4*dg..4*dg+3 over k-slice
// 16*ks..16*ks+15 with float4 G-row loads shared by both batch rows; k-slice
// partials reduced through LDS. Scores/sum/store per row as before.
// ---------------------------------------------------------------------------
__global__ __launch_bounds__(256) void att_fused2(
    const float* __restrict__ S, const float* __restrict__ T,
    const float* __restrict__ P, float* out)
{
    const int t  = threadIdx.x;
    const int b0 = blockIdx.x * 2;
    const int b1 = b0 + 1;
    const int lc = t & 31;   // float4 chunk within row (d = lc*4 .. lc*4+3)
    const int eb = t >> 5;   // 0..7, edge within iteration group

    __shared__ float Tl0[D], Tl1[D];
    __shared__ f32x4 vl0[8][32], vl1[8][32];   // k-slice GEMV partials
    __shared__ float sc0[E], sc1[E];
    __shared__ float inv0, inv1, c_s0, c_s1;

    const f32x4* Sp = (const f32x4*)S;

    // Issue the HBM stream first: 32 independent nt loads per thread.
    f32x4 s0[16], s1[16];
    #pragma unroll
    for (int i = 0; i < 16; ++i) {
        const size_t eoff = (size_t)(i * 8 + eb) * BB;
        s0[i] = __builtin_nontemporal_load(Sp + (eoff + b0) * 32 + lc);
        s1[i] = __builtin_nontemporal_load(Sp + (eoff + b1) * 32 + lc);
    }

    // Stage the two T rows (one wave).
    if (t < 32)       ((f32x4*)Tl0)[t]      = ((const f32x4*)(T + (size_t)b0 * D))[t];
    else if (t < 64)  ((f32x4*)Tl1)[t - 32] = ((const f32x4*)(T + (size_t)b1 * D))[t - 32];
    __syncthreads();

    // GEMV partials: 16 float4 G loads, each feeding both rows.
    {
        const int dg = t & 31, ks = t >> 5;
        const f32x4* P4 = (const f32x4*)P;
        f32x4 a0 = {0.f, 0.f, 0.f, 0.f}, a1 = a0;
        #pragma unroll
        for (int kk = 0; kk < 16; ++kk) {
            const int k = ks * 16 + kk;
            const f32x4 g4 = P4[(size_t)k * 32 + dg];   // G[k][4dg..4dg+3]
            a0 += Tl0[k] * g4;                          // LDS broadcast
            a1 += Tl1[k] * g4;
        }
        vl0[ks][dg] = a0;
        vl1[ks][dg] = a1;
    }
    // c = T.h + beta : lanes 0..31 -> b0, lanes 32..63 -> b1 (wave 0).
    if (t < 64) {
        const int cl = t & 31;
        const float* Trow = (t < 32) ? Tl0 : Tl1;
        const f32x4 tc = ((const f32x4*)Trow)[cl];
        const f32x4 hc = ((const f32x4*)(P + D * D))[cl];
        float p = tc.x * hc.x + tc.y * hc.y + tc.z * hc.z + tc.w * hc.w;
        #pragma unroll
        for (int m = 16; m >= 1; m >>= 1) p += __shfl_xor(p, m);
        if (t == 0)  c_s0 = p + P[D * D + D];
        if (t == 32) c_s1 = p + P[D * D + D];
    }
    __syncthreads();

    // Assemble per-thread v chunks (d = lc*4 .. lc*4+3) for both rows.
    f32x4 v0, v1;
    {
        const f32x4 h4 = ((const f32x4*)(P + D * D))[lc];
        f32x4 r0 = h4, r1 = h4;
        #pragma unroll
        for (int ks = 0; ks < 8; ++ks) { r0 += vl0[ks][lc]; r1 += vl1[ks][lc]; }
        v0 = r0; v1 = r1;
    }
    const float cc0 = c_s0, cc1 = c_s1;

    // Scores: per-lane dot4, butterfly over the 32 lanes of the d-dimension.
    #pragma unroll
    for (int i = 0; i < 16; ++i) {
        float p0 = s0[i].x * v0.x + s0[i].y * v0.y + s0[i].z * v0.z + s0[i].w * v0.w;
        float p1 = s1[i].x * v1.x + s1[i].y * v1.y + s1[i].z * v1.z + s1[i].w * v1.w;
        #pragma unroll
        for (int m = 16; m >= 1; m >>= 1) {
            p0 += __shfl_xor(p0, m);
            p1 += __shfl_xor(p1, m);
        }
        if (lc == 0) { sc0[i * 8 + eb] = p0 + cc0; sc1[i * 8 + eb] = p1 + cc1; }
    }
    __syncthreads();

    // Edge sums in double: wave 0 -> b0, wave 1 -> b1.
    if (t < 64) {
        double d0 = (double)sc0[t] + (double)sc0[t + 64];
        #pragma unroll
        for (int m = 32; m >= 1; m >>= 1) d0 += __shfl_xor(d0, m);
        if (t == 0) inv0 = (float)(1.0 / d0);
    } else if (t < 128) {
        const int tl = t - 64;
        double d1 = (double)sc1[tl] + (double)sc1[tl + 64];
        #pragma unroll
        for (int m = 32; m >= 1; m >>= 1) d1 += __shfl_xor(d1, m);
        if (t == 64) inv1 = (float)(1.0 / d1);
    }
    __syncthreads();

    const float i0 = inv0, i1 = inv1;
    f32x4* Op = (f32x4*)out;
    #pragma unroll
    for (int i = 0; i < 16; ++i) {
        const size_t eoff = (size_t)(i * 8 + eb) * BB;
        const float w0 = sc0[i * 8 + eb] * i0;
        const float w1 = sc1[i * 8 + eb] * i1;
        __builtin_nontemporal_store(s0[i] * w0, Op + (eoff + b0) * 32 + lc);
        __builtin_nontemporal_store(s1[i] * w1, Op + (eoff + b1) * 32 + lc);
    }
}

// ---------------------------------------------------------------------------
// Fallback path (ws absent/too small): prep2 + att_main, scratch in d_out.
//   v[b,:] at out[b*D ...] (e=0), c[b] at out[(BB+b)*D] (e=1), P at e=2 head.
// ---------------------------------------------------------------------------
__global__ __launch_bounds__(256) void prep2_kernel(
    const float* __restrict__ T, const float* __restrict__ P, float* out)
{
    __shared__ float Gl[D][D];      // 64 KB
    __shared__ float Tl[ROWS][D];   // 4 KB
    __shared__ float hl[D];
    __shared__ float beta_s;

    const int t  = threadIdx.x;
    const int b0 = blockIdx.x * ROWS;

    {
        const float4* Gs = (const float4*)P;
        float4* Gd = (float4*)&Gl[0][0];
        for (int i = t; i < D * D / 4; i += 256) Gd[i] = Gs[i];
        const float4* Ts = (const float4*)(T + (size_t)b0 * D);
        ((float4*)&Tl[0][0])[t] = Ts[t];          // 256 float4 == ROWS*D
        if (t < D) hl[t] = P[D * D + t];
        if (t == 0) beta_s = P[D * D + D];
    }
    __syncthreads();

    const int dc = t & 127;          // output column d
    const int r0 = (t >> 7) * 4;     // this thread's 4 rows
    float a0 = hl[dc], a1 = hl[dc], a2 = hl[dc], a3 = hl[dc];
    #pragma unroll 4
    for (int k = 0; k < D; k += 4) {
        const float g0 = Gl[k + 0][dc], g1 = Gl[k + 1][dc],
                    g2 = Gl[k + 2][dc], g3 = Gl[k + 3][dc];
        const float4 t0 = *(const float4*)&Tl[r0 + 0][k];
        const float4 t1 = *(const float4*)&Tl[r0 + 1][k];
        const float4 t2 = *(const float4*)&Tl[r0 + 2][k];
        const float4 t3 = *(const float4*)&Tl[r0 + 3][k];
        a0 += t0.x * g0 + t0.y * g1 + t0.z * g2 + t0.w * g3;
        a1 += t1.x * g0 + t1.y * g1 + t1.z * g2 + t1.w * g3;
        a2 += t2.x * g0 + t2.y * g1 + t2.z * g2 + t2.w * g3;
        a3 += t3.x * g0 + t3.y * g1 + t3.z * g2 + t3.w * g3;
    }
    out[(size_t)(b0 + r0 + 0) * D + dc] = a0;
    out[(size_t)(b0 + r0 + 1) * D + dc] = a1;
    out[(size_t)(b0 + r0 + 2) * D + dc] = a2;
    out[(size_t)(b0 + r0 + 3) * D + dc] = a3;

    const int cr = t >> 5, cl = t & 31;
    const float4 tc = *(const float4*)&Tl[cr][cl * 4];
    const float4 hc = *(const float4*)&hl[cl * 4];
    float p = tc.x * hc.x + tc.y * hc.y + tc.z * hc.z + tc.w * hc.w;
    #pragma unroll
    for (int msk = 16; msk >= 1; msk >>= 1) p += __shfl_xor(p, msk);
    if (cl == 0) out[(size_t)(BB + b0 + cr) * D] = p + beta_s;
}

__global__ __launch_bounds__(256) void att_main(
    const float* __restrict__ S, float* out)
{
    const int b  = blockIdx.x;
    const int t  = threadIdx.x;
    const int lc = t & 31;
    const int eb = t >> 5;

    __shared__ float sc[E];
    __shared__ float inv_s;

    const f32x4* Sp = (const f32x4*)S;
    const f32x4  v4 = ((const f32x4*)(out + (size_t)b * D))[lc];
    const float  c  = out[(size_t)(BB + b) * D];

    f32x4 s[16];
    #pragma unroll
    for (int i = 0; i < 16; ++i) {
        const int e = i * 8 + eb;
        s[i] = __builtin_nontemporal_load(Sp + ((size_t)e * BB + b) * 32 + lc);
    }

    #pragma unroll
    for (int i = 0; i < 16; ++i) {
        float p = s[i].x * v4.x + s[i].y * v4.y + s[i].z * v4.z + s[i].w * v4.w;
        #pragma unroll
        for (int msk = 16; msk >= 1; msk >>= 1) p += __shfl_xor(p, msk);
        if (lc == 0) sc[i * 8 + eb] = p + c;
    }
    __syncthreads();

    if (t < 64) {
        double d0 = (double)sc[t] + (double)sc[t + 64];
        #pragma unroll
        for (int msk = 32; msk >= 1; msk >>= 1) d0 += __shfl_xor(d0, msk);
        if (t == 0) inv_s = (float)(1.0 / d0);
    }
    __syncthreads();

    const float inv = inv_s;
    f32x4* Op = (f32x4*)out;
    #pragma unroll
    for (int i = 0; i < 16; ++i) {
        const int e = i * 8 + eb;
        const float w = sc[e] * inv;
        __builtin_nontemporal_store(s[i] * w, Op + ((size_t)e * BB + b) * 32 + lc);
    }
}

extern "C" void kernel_launch(void* const* d_in, const int* in_sizes, int n_in,
                              void* d_out, int out_size, void* d_ws, size_t ws_size,
                              hipStream_t stream) {
    // d_in: [0]=true_batch_size(int,1) [1]=T[B,D] [2]=S[E,B,D] [3]=W[D,D] [4]=b[D]
    const float* T    = (const float*)d_in[1];
    const float* S    = (const float*)d_in[2];
    const float* W    = (const float*)d_in[3];
    const float* bias = (const float*)d_in[4];
    float* out        = (float*)d_out;

    const size_t need = (size_t)(D * D + D + 1) * sizeof(float);
    if (d_ws != nullptr && ws_size >= need) {
        float* P = (float*)d_ws;
        gwh_kernel<<<D, D, 0, stream>>>(W, bias, P);
        att_fused2<<<BB / 2, 256, 0, stream>>>(S, T, P, out);
    } else {
        float* P = out + (size_t)2 * BB * D;   // e=2 slice head (stream-ordered)
        gwh_kernel<<<D, D, 0, stream>>>(W, bias, P);
        prep2_kernel<<<BB / ROWS, 256, 0, stream>>>(T, P, out);
        att_main<<<BB, 256, 0, stream>>>(S, out);
    }
}